// Round 1
// baseline (241.877 us; speedup 1.0000x reference)
//
#include <hip/hip_runtime.h>
#include <hip/hip_bf16.h>
#include <stdint.h>

// CostVolumeAttention2: B=2, N=8192, C=512, heads=8, hd=64, T=8, H=W=32, U=49.
// Linearized softmax: |M|<=49/64^2=0.012 -> exp(M)=1+M to 7e-5 rel accuracy.
// attn @ v collapses to rank-50:  num = A'^T (A' v),  den = A'^T (A' 1),
// where A' = corr with an appended ones-row (u=49), zero pad to 64 rows.

#define DEVFN __device__ __forceinline__

typedef __attribute__((ext_vector_type(8))) short bf16x8;
typedef __attribute__((ext_vector_type(4))) float f32x4;

DEVFN float bf2f(short s) {
  union { unsigned int u; float f; } v;
  v.u = ((unsigned int)(unsigned short)s) << 16;
  return v.f;
}
DEVFN short f2bf(float f) {
  __hip_bfloat16 h = __float2bfloat16(f);
  return *reinterpret_cast<short*>(&h);
}

DEVFN void gl_lds16(const void* g, void* l) {
  __builtin_amdgcn_global_load_lds((const __attribute__((address_space(1))) void*)g,
                                   (__attribute__((address_space(3))) void*)l, 16, 0, 0);
}

#define MFMA(a, b, c) __builtin_amdgcn_mfma_f32_16x16x32_bf16((a), (b), (c), 0, 0, 0)

#define NTOK 8192
#define HW   1024

// ---------------------------------------------------------------- fp32->bf16
__global__ void k_cvt(const float* __restrict__ in, short* __restrict__ out, int n8) {
  int i = blockIdx.x * blockDim.x + threadIdx.x;
  if (i >= n8) return;
  const float4* p = (const float4*)in + (size_t)i * 2;
  float4 a = p[0], b = p[1];
  bf16x8 r;
  r[0]=f2bf(a.x); r[1]=f2bf(a.y); r[2]=f2bf(a.z); r[3]=f2bf(a.w);
  r[4]=f2bf(b.x); r[5]=f2bf(b.y); r[6]=f2bf(b.z); r[7]=f2bf(b.w);
  *(bf16x8*)(out + (size_t)i * 8) = r;
}

// ------------------------------------------------- GEMM: C[M][N] = A * B^T
// A: [M][K] bf16, B: [N][K] bf16 (row-major, k-contiguous). 128x128 tile, BK=64.
// LDS source-XOR swizzle (byte ^= (row&7)<<4) to break 128B-row bank conflicts.
template<int F32OUT>
__global__ __launch_bounds__(256, 2) void k_gemm_bt(
    const short* __restrict__ A, const short* __restrict__ Bm,
    void* __restrict__ Cp, const float* __restrict__ bias, int M, int N, int K)
{
  __shared__ short lA[128 * 64];
  __shared__ short lB[128 * 64];
  const int tid = threadIdx.x;
  const int lane = tid & 63, w = tid >> 6;
  const int wm = w >> 1, wn = w & 1;
  const int r15 = lane & 15, hi = (lane >> 4) * 16, g4 = (lane >> 4) * 4;
  const int m0 = blockIdx.y * 128, n0 = blockIdx.x * 128;

  f32x4 acc[4][4];
#pragma unroll
  for (int i = 0; i < 4; i++)
#pragma unroll
    for (int j = 0; j < 4; j++) acc[i][j] = (f32x4)0.f;

  for (int k0 = 0; k0 < K; k0 += 64) {
#pragma unroll
    for (int it = 0; it < 4; it++) {
      int chunk = it * 256 + tid;
      int row = chunk >> 3;
      int sb = ((chunk & 7) * 16) ^ ((row & 7) << 4);
      const char* srcA = (const char*)(A + (size_t)(m0 + row) * K + k0) + sb;
      const char* srcB = (const char*)(Bm + (size_t)(n0 + row) * K + k0) + sb;
      short* dA = lA + (it * 256 + w * 64) * 8;   // wave-uniform base, lane*16 implicit
      short* dB = lB + (it * 256 + w * 64) * 8;
      gl_lds16(srcA, dA);
      gl_lds16(srcB, dB);
    }
    asm volatile("s_waitcnt vmcnt(0)" ::: "memory");
    __syncthreads();

    bf16x8 af[4][2], bfr[4][2];
#pragma unroll
    for (int mt = 0; mt < 4; mt++) {
      int row = wm * 64 + mt * 16 + r15;
#pragma unroll
      for (int kh = 0; kh < 2; kh++) {
        int off = row * 128 + ((kh * 64 + hi) ^ ((row & 7) << 4));
        af[mt][kh] = *(const bf16x8*)((const char*)lA + off);
      }
    }
#pragma unroll
    for (int nt = 0; nt < 4; nt++) {
      int row = wn * 64 + nt * 16 + r15;
#pragma unroll
      for (int kh = 0; kh < 2; kh++) {
        int off = row * 128 + ((kh * 64 + hi) ^ ((row & 7) << 4));
        bfr[nt][kh] = *(const bf16x8*)((const char*)lB + off);
      }
    }
#pragma unroll
    for (int mt = 0; mt < 4; mt++)
#pragma unroll
      for (int nt = 0; nt < 4; nt++) {
        acc[mt][nt] = MFMA(af[mt][0], bfr[nt][0], acc[mt][nt]);
        acc[mt][nt] = MFMA(af[mt][1], bfr[nt][1], acc[mt][nt]);
      }
    __syncthreads();
  }

#pragma unroll
  for (int mt = 0; mt < 4; mt++)
#pragma unroll
    for (int j = 0; j < 4; j++) {
      int row = m0 + wm * 64 + mt * 16 + g4 + j;
#pragma unroll
      for (int nt = 0; nt < 4; nt++) {
        int col = n0 + wn * 64 + nt * 16 + r15;
        float v = acc[mt][nt][j];
        if (F32OUT) ((float*)Cp)[(size_t)row * N + col] = v + bias[col];
        else        ((short*)Cp)[(size_t)row * N + col] = f2bf(v);
      }
    }
}

// ---------------------------------------------------------------- cost volume
// One WG per (bht, y). Gram q_row(32px) x k_rows(7x32px) via MFMA on RAW bf16,
// norms folded into the output scale: corr = dot * (1/(8 nq)) * (1/(8 nk)).
// Writes corrI[bht][i][u(pad 64, u49=1, u>49=0)] and corrU[bht][u][i].
__global__ __launch_bounds__(256, 2) void k_corr(
    const short* __restrict__ qkvb, short* __restrict__ corrI, short* __restrict__ corrU)
{
  __shared__ short lq[32 * 64];    // q row, swizzled rows of 128B
  __shared__ short lk[224 * 64];   // k rows p = dy*32+xx
  __shared__ float sq[32];
  __shared__ float sk[224];

  const int tid = threadIdx.x;
  const int lane = tid & 63, w = tid >> 6;
  const int r15 = lane & 15, hi = (lane >> 4) * 16, g4 = (lane >> 4) * 4;
  const int y = blockIdx.x & 31, bht = blockIdx.x >> 5;
  const int b = bht >> 6, head = (bht >> 3) & 7, tf = bht & 7;
  const int tk = (tf < 7) ? tf + 1 : 7;

  { // stage q: 32 rows x 128B = 256 chunks (1/thread)
    int row = tid >> 3;
    int sb = ((tid & 7) * 16) ^ ((row & 7) << 4);
    const char* src = (const char*)(qkvb + ((size_t)b * NTOK + tf * HW + y * 32 + row) * 1536 + head * 64) + sb;
    gl_lds16(src, lq + (w * 64) * 8);
  }
#pragma unroll
  for (int it = 0; it < 7; it++) { // stage k: 224 rows = 1792 chunks (7/thread)
    int chunk = it * 256 + tid;
    int row = chunk >> 3;          // p = dy*32+xx
    int dy = row >> 5, xx = row & 31;
    int ysrc = y + dy - 3;
    int sb = ((chunk & 7) * 16) ^ ((row & 7) << 4);
    short* dstbase = lk + (it * 256 + w * 64) * 8;
    if (ysrc >= 0 && ysrc < 32) {
      const char* src = (const char*)(qkvb + ((size_t)b * NTOK + tk * HW + ysrc * 32 + xx) * 1536 + 512 + head * 64) + sb;
      gl_lds16(src, dstbase);
    } else {
      *(bf16x8*)(lk + (size_t)chunk * 8) = (bf16x8)(short)0;  // zero pad (swizzle moot)
    }
  }
  asm volatile("s_waitcnt vmcnt(0)" ::: "memory");
  __syncthreads();

  { // norms: thread t<32 -> q pixel t; else k pixel t-32. scale = 1/(8*max(n,eps))
    int r = (tid < 32) ? tid : tid - 32;
    const short* base = (tid < 32) ? lq : lk;
    float ss = 0.f;
#pragma unroll
    for (int jj = 0; jj < 8; jj++) {
      int off = r * 128 + ((jj * 16) ^ ((r & 7) << 4));
      bf16x8 vv = *(const bf16x8*)((const char*)base + off);
#pragma unroll
      for (int e = 0; e < 8; e++) { float f = bf2f(vv[e]); ss += f * f; }
    }
    float nrm = fmaxf(sqrtf(ss), 1e-12f);
    float sc = 1.f / (8.f * nrm);
    if (tid < 32) sq[tid] = sc; else sk[tid - 32] = sc;
  }
  __syncthreads();

  // MFMA: 2 m-tiles x 14 n-tiles, wave w owns tiles t = w*7 .. w*7+6
  bf16x8 aq[2][2];
#pragma unroll
  for (int mt = 0; mt < 2; mt++) {
    int row = mt * 16 + r15;
#pragma unroll
    for (int kh = 0; kh < 2; kh++) {
      int off = row * 128 + ((kh * 64 + hi) ^ ((row & 7) << 4));
      aq[mt][kh] = *(const bf16x8*)((const char*)lq + off);
    }
  }
  f32x4 accc[7];
#pragma unroll
  for (int c = 0; c < 7; c++) {
    int t = w * 7 + c, mt = t & 1, nt = t >> 1;
    int rowB = nt * 16 + r15;
    f32x4 a = (f32x4)0.f;
#pragma unroll
    for (int kh = 0; kh < 2; kh++) {
      int off = rowB * 128 + ((kh * 64 + hi) ^ ((rowB & 7) << 4));
      bf16x8 bb = *(const bf16x8*)((const char*)lk + off);
      a = MFMA(aq[mt][kh], bb, a);
    }
    accc[c] = a;
  }

  // extract banded diagonals: acc[x][p], p=dy*32+xx, keep |xx-x|<=3
#pragma unroll
  for (int c = 0; c < 7; c++) {
    int t = w * 7 + c, mt = t & 1, nt = t >> 1;
    int p = nt * 16 + r15;
    int dy = p >> 5, xx = p & 31;
    float skv = sk[p];
#pragma unroll
    for (int j = 0; j < 4; j++) {
      int xr = mt * 16 + g4 + j;
      int dx = xx - xr + 3;
      if (dx >= 0 && dx < 7) {
        int u = dy * 7 + dx;
        short bv = f2bf(accc[c][j] * sq[xr] * skv);
        int i = y * 32 + xr;
        corrI[((size_t)bht * HW + i) * 64 + u] = bv;
        corrU[(size_t)bht * 65536 + u * HW + i] = bv;
      }
    }
  }
  { // pad u=49 (ones) and u=50..63 (zeros)
    int x = tid >> 3, r = tid & 7;
    int i = y * 32 + x;
    for (int uu = 49 + r; uu < 64; uu += 8) {
      short bv = (uu == 49) ? f2bf(1.f) : (short)0;
      corrI[((size_t)bht * HW + i) * 64 + uu] = bv;
      corrU[(size_t)bht * 65536 + uu * HW + i] = bv;
    }
  }
}

// ----------------------------------------------- v transpose: vT[bht][d][i]
__global__ __launch_bounds__(256, 2) void k_vT(const short* __restrict__ qkvb, short* __restrict__ vT)
{
  __shared__ short lt[128 * 72];  // [i][d] pad 72
  const int tid = threadIdx.x;
  const int bht = blockIdx.x;
  const int b = bht >> 6, head = (bht >> 3) & 7, tf = bht & 7;
  const size_t rowbase = ((size_t)b * NTOK + tf * HW) * 1536 + 1024 + head * 64;
  for (int c0 = 0; c0 < 1024; c0 += 128) {
    __syncthreads();
#pragma unroll
    for (int it = 0; it < 4; it++) {
      int idx = it * 256 + tid;
      int row = idx >> 3, part = idx & 7;
      bf16x8 v = *(const bf16x8*)(qkvb + rowbase + (size_t)(c0 + row) * 1536 + part * 8);
      *(bf16x8*)(lt + row * 72 + part * 8) = v;
    }
    __syncthreads();
    int d = tid & 63, blk = tid >> 6;
#pragma unroll
    for (int qq = 0; qq < 4; qq++) {
      bf16x8 o;
#pragma unroll
      for (int e = 0; e < 8; e++) o[e] = lt[(blk * 32 + qq * 8 + e) * 72 + d];
      *(bf16x8*)(vT + ((size_t)bht * 64 + d) * HW + c0 + blk * 32 + qq * 8) = o;
    }
  }
}

// ----------------------------------------------- c1[bht][u] = sum_i corrU[u][i]
__global__ __launch_bounds__(256, 1) void k_c1(const short* __restrict__ corrU, float* __restrict__ c1)
{
  const int bht = blockIdx.x;
  const int tid = threadIdx.x, lane = tid & 63, w = tid >> 6;
  for (int r = 0; r < 16; r++) {
    int u = w * 16 + r;
    const short* row = corrU + (size_t)bht * 65536 + u * HW;
    float s = 0.f;
#pragma unroll
    for (int cc = 0; cc < 2; cc++) {
      bf16x8 v = *(const bf16x8*)(row + (cc * 64 + lane) * 8);
#pragma unroll
      for (int e = 0; e < 8; e++) s += bf2f(v[e]);
    }
    for (int off = 32; off; off >>= 1) s += __shfl_xor(s, off);
    if (lane == 0) c1[bht * 64 + u] = s;
  }
}

// --------------------------------- fused rank-50 attention, one WG per bht
// phase1: GT[d][u] = sum_i vT[d][i]*corrU[u][i]   (K=1024, MFMA)
// phase2: out[i][d] = (corrI[i][:] . GT[d][:]) / (corrI[i][:] . c1[:])
__global__ __launch_bounds__(256, 2) void k_attn(
    const short* __restrict__ corrU, const short* __restrict__ corrI,
    const short* __restrict__ vT, const float* __restrict__ c1,
    short* __restrict__ out_attn)
{
  __shared__ short lV[64 * 64];
  __shared__ short lU[64 * 64];
  __shared__ short GTl[64 * 72];
  __shared__ float cl[64];
  const int tid = threadIdx.x, lane = tid & 63, w = tid >> 6;
  const int r15 = lane & 15, hi = (lane >> 4) * 16, g4 = (lane >> 4) * 4, g8 = (lane >> 4) * 8;
  const int bht = blockIdx.x;
  const int b = bht >> 6, head = (bht >> 3) & 7, tf = bht & 7;

  if (tid < 64) cl[tid] = c1[bht * 64 + tid];

  f32x4 accP[4];
#pragma unroll
  for (int nt = 0; nt < 4; nt++) accP[nt] = (f32x4)0.f;
  const short* vbase = vT + (size_t)bht * 64 * HW;
  const short* ubase = corrU + (size_t)bht * 65536;

  for (int i0 = 0; i0 < 1024; i0 += 64) {
#pragma unroll
    for (int it = 0; it < 2; it++) {
      int chunk = it * 256 + tid;
      int row = chunk >> 3;
      int sb = ((chunk & 7) * 16) ^ ((row & 7) << 4);
      gl_lds16((const char*)(vbase + (size_t)row * HW + i0) + sb, lV + (it * 256 + w * 64) * 8);
      gl_lds16((const char*)(ubase + (size_t)row * HW + i0) + sb, lU + (it * 256 + w * 64) * 8);
    }
    asm volatile("s_waitcnt vmcnt(0)" ::: "memory");
    __syncthreads();
    bf16x8 av[2];
    int rowA = w * 16 + r15;
#pragma unroll
    for (int kh = 0; kh < 2; kh++) {
      int off = rowA * 128 + ((kh * 64 + hi) ^ ((rowA & 7) << 4));
      av[kh] = *(const bf16x8*)((const char*)lV + off);
    }
#pragma unroll
    for (int nt = 0; nt < 4; nt++) {
      int rowB = nt * 16 + r15;
#pragma unroll
      for (int kh = 0; kh < 2; kh++) {
        int off = rowB * 128 + ((kh * 64 + hi) ^ ((rowB & 7) << 4));
        bf16x8 bu = *(const bf16x8*)((const char*)lU + off);
        accP[nt] = MFMA(av[kh], bu, accP[nt]);
      }
    }
    __syncthreads();
  }
#pragma unroll
  for (int nt = 0; nt < 4; nt++)
#pragma unroll
    for (int j = 0; j < 4; j++) {
      int d = w * 16 + g4 + j, u = nt * 16 + r15;
      GTl[d * 72 + u] = f2bf(accP[nt][j]);
    }
  __syncthreads();

  bf16x8 gtb[4][2];
#pragma unroll
  for (int nt = 0; nt < 4; nt++)
#pragma unroll
    for (int kh = 0; kh < 2; kh++)
      gtb[nt][kh] = *(const bf16x8*)((const char*)GTl + (nt * 16 + r15) * 144 + kh * 64 + hi);

  float c1r[2][8];
#pragma unroll
  for (int kh = 0; kh < 2; kh++)
#pragma unroll
    for (int e = 0; e < 8; e++) c1r[kh][e] = cl[kh * 32 + g8 + e];

  const short* ibase = corrI + (size_t)bht * HW * 64;
  for (int s = 0; s < 16; s++) {
    int i0 = w * 256 + s * 16;
    bf16x8 af[2];
#pragma unroll
    for (int kh = 0; kh < 2; kh++)
      af[kh] = *(const bf16x8*)(ibase + (size_t)(i0 + r15) * 64 + kh * 32 + g8);
    f32x4 a2[4];
#pragma unroll
    for (int nt = 0; nt < 4; nt++) a2[nt] = (f32x4)0.f;
#pragma unroll
    for (int nt = 0; nt < 4; nt++)
#pragma unroll
      for (int kh = 0; kh < 2; kh++) a2[nt] = MFMA(af[kh], gtb[nt][kh], a2[nt]);

    float dp = 0.f;
#pragma unroll
    for (int kh = 0; kh < 2; kh++)
#pragma unroll
      for (int e = 0; e < 8; e++) dp += bf2f(af[kh][e]) * c1r[kh][e];
    dp += __shfl_xor(dp, 16);
    dp += __shfl_xor(dp, 32);   // lanes sharing (lane&15) now hold full denom of row i0+(lane&15)

#pragma unroll
    for (int j = 0; j < 4; j++) {
      float dj = __shfl(dp, g4 + j);
      float inv = 1.f / dj;
      int i = i0 + g4 + j;
      size_t outrow = ((size_t)b * NTOK + tf * HW + i) * 512 + head * 64;
#pragma unroll
      for (int nt = 0; nt < 4; nt++)
        out_attn[outrow + nt * 16 + r15] = f2bf(a2[nt][j] * inv);
    }
  }
}

extern "C" void kernel_launch(void* const* d_in, const int* in_sizes, int n_in,
                              void* d_out, int out_size, void* d_ws, size_t ws_size,
                              hipStream_t stream) {
  (void)in_sizes; (void)n_in; (void)out_size; (void)ws_size;
  const float* x      = (const float*)d_in[0];
  const float* w_qkv  = (const float*)d_in[1];
  const float* w_proj = (const float*)d_in[2];
  const float* b_proj = (const float*)d_in[3];

  char* ws = (char*)d_ws;                       // total needed: ~98.0 MB
  short* qkvb   = (short*)(ws);                 // 50,331,648 B [16384][1536]
  short* xb     = (short*)(ws + 50331648);      // 16,777,216 B
  short* corrU  = (short*)(ws + 67108864);      // 16,777,216 B [128][64][1024]
  short* vT     = (short*)(ws + 83886080);      // 16,777,216 B [128][64][1024]
  short* wqkvb  = (short*)(ws + 100663296);     //  1,572,864 B
  short* wprojb = (short*)(ws + 102236160);     //    524,288 B
  float* c1     = (float*)(ws + 102760448);     //     32,768 B
  short* corrI    = xb;    // alias: xb dead after qkv GEMM
  short* out_attn = qkvb;  // alias: qkvb dead after corr + vT

  k_cvt<<<dim3(4096), 256, 0, stream>>>(x, xb, 1048576);
  k_cvt<<<dim3(384),  256, 0, stream>>>(w_qkv, wqkvb, 98304);
  k_cvt<<<dim3(128),  256, 0, stream>>>(w_proj, wprojb, 32768);

  k_gemm_bt<0><<<dim3(12, 128), 256, 0, stream>>>(xb, wqkvb, qkvb, nullptr, 16384, 1536, 512);

  k_corr<<<dim3(4096), 256, 0, stream>>>(qkvb, corrI, corrU);
  k_vT<<<dim3(128), 256, 0, stream>>>(qkvb, vT);
  k_c1<<<dim3(128), 256, 0, stream>>>(corrU, c1);

  k_attn<<<dim3(128), 256, 0, stream>>>(corrU, corrI, vT, c1, out_attn);

  k_gemm_bt<1><<<dim3(4, 128), 256, 0, stream>>>(out_attn, wprojb, d_out, b_proj, 16384, 512, 512);
}

// Round 2
// 235.537 us; speedup vs baseline: 1.0269x; 1.0269x over previous
//
#include <hip/hip_runtime.h>
#include <hip/hip_bf16.h>
#include <stdint.h>

// CostVolumeAttention2: B=2, N=8192, C=512, heads=8, hd=64, T=8, H=W=32, U=49.
// Linearized softmax: |M|<=49/64^2=0.012 -> exp(M)=1+M to 7e-5 rel accuracy.
// attn @ v collapses to rank-50:  num = A'^T (A' v),  den = A'^T (A' 1),
// where A' = corr with an appended ones-row (u=49), zero pad to 64 rows.

#define DEVFN __device__ __forceinline__

typedef __attribute__((ext_vector_type(8))) short bf16x8;
typedef __attribute__((ext_vector_type(4))) float f32x4;

DEVFN float bf2f(short s) {
  union { unsigned int u; float f; } v;
  v.u = ((unsigned int)(unsigned short)s) << 16;
  return v.f;
}
DEVFN short f2bf(float f) {
  __hip_bfloat16 h = __float2bfloat16(f);
  return *reinterpret_cast<short*>(&h);
}

DEVFN void gl_lds16(const void* g, void* l) {
  __builtin_amdgcn_global_load_lds((const __attribute__((address_space(1))) void*)g,
                                   (__attribute__((address_space(3))) void*)l, 16, 0, 0);
}

#define MFMA(a, b, c) __builtin_amdgcn_mfma_f32_16x16x32_bf16((a), (b), (c), 0, 0, 0)

#define NTOK 8192
#define HW   1024

// ---------------------------------------------------------------- fp32->bf16
__global__ void k_cvt(const float* __restrict__ in, short* __restrict__ out, int n8) {
  int i = blockIdx.x * blockDim.x + threadIdx.x;
  if (i >= n8) return;
  const float4* p = (const float4*)in + (size_t)i * 2;
  float4 a = p[0], b = p[1];
  bf16x8 r;
  r[0]=f2bf(a.x); r[1]=f2bf(a.y); r[2]=f2bf(a.z); r[3]=f2bf(a.w);
  r[4]=f2bf(b.x); r[5]=f2bf(b.y); r[6]=f2bf(b.z); r[7]=f2bf(b.w);
  *(bf16x8*)(out + (size_t)i * 8) = r;
}

// ------------------------------------------------- GEMM: C[M][N] = A * B^T
// A: [M][K] bf16, B: [N][K] bf16 (row-major, k-contiguous). 128x128 tile, BK=64.
// LDS source-XOR swizzle (byte ^= (row&7)<<4) to break 128B-row bank conflicts.
template<int F32OUT>
__global__ __launch_bounds__(256, 2) void k_gemm_bt(
    const short* __restrict__ A, const short* __restrict__ Bm,
    void* __restrict__ Cp, const float* __restrict__ bias, int M, int N, int K)
{
  __shared__ short lA[128 * 64];
  __shared__ short lB[128 * 64];
  const int tid = threadIdx.x;
  const int lane = tid & 63, w = tid >> 6;
  const int wm = w >> 1, wn = w & 1;
  const int r15 = lane & 15, hi = (lane >> 4) * 16, g4 = (lane >> 4) * 4;
  const int m0 = blockIdx.y * 128, n0 = blockIdx.x * 128;

  f32x4 acc[4][4];
#pragma unroll
  for (int i = 0; i < 4; i++)
#pragma unroll
    for (int j = 0; j < 4; j++) acc[i][j] = (f32x4)0.f;

  for (int k0 = 0; k0 < K; k0 += 64) {
#pragma unroll
    for (int it = 0; it < 4; it++) {
      int chunk = it * 256 + tid;
      int row = chunk >> 3;
      int sb = ((chunk & 7) * 16) ^ ((row & 7) << 4);
      const char* srcA = (const char*)(A + (size_t)(m0 + row) * K + k0) + sb;
      const char* srcB = (const char*)(Bm + (size_t)(n0 + row) * K + k0) + sb;
      short* dA = lA + (it * 256 + w * 64) * 8;   // wave-uniform base, lane*16 implicit
      short* dB = lB + (it * 256 + w * 64) * 8;
      gl_lds16(srcA, dA);
      gl_lds16(srcB, dB);
    }
    asm volatile("s_waitcnt vmcnt(0)" ::: "memory");
    __syncthreads();

    bf16x8 af[4][2], bfr[4][2];
#pragma unroll
    for (int mt = 0; mt < 4; mt++) {
      int row = wm * 64 + mt * 16 + r15;
#pragma unroll
      for (int kh = 0; kh < 2; kh++) {
        int off = row * 128 + ((kh * 64 + hi) ^ ((row & 7) << 4));
        af[mt][kh] = *(const bf16x8*)((const char*)lA + off);
      }
    }
#pragma unroll
    for (int nt = 0; nt < 4; nt++) {
      int row = wn * 64 + nt * 16 + r15;
#pragma unroll
      for (int kh = 0; kh < 2; kh++) {
        int off = row * 128 + ((kh * 64 + hi) ^ ((row & 7) << 4));
        bfr[nt][kh] = *(const bf16x8*)((const char*)lB + off);
      }
    }
#pragma unroll
    for (int mt = 0; mt < 4; mt++)
#pragma unroll
      for (int nt = 0; nt < 4; nt++) {
        acc[mt][nt] = MFMA(af[mt][0], bfr[nt][0], acc[mt][nt]);
        acc[mt][nt] = MFMA(af[mt][1], bfr[nt][1], acc[mt][nt]);
      }
    __syncthreads();
  }

#pragma unroll
  for (int mt = 0; mt < 4; mt++)
#pragma unroll
    for (int j = 0; j < 4; j++) {
      int row = m0 + wm * 64 + mt * 16 + g4 + j;
#pragma unroll
      for (int nt = 0; nt < 4; nt++) {
        int col = n0 + wn * 64 + nt * 16 + r15;
        float v = acc[mt][nt][j];
        if (F32OUT) ((float*)Cp)[(size_t)row * N + col] = v + bias[col];
        else        ((short*)Cp)[(size_t)row * N + col] = f2bf(v);
      }
    }
}

// ---------------------------------------------------------------- cost volume
// One WG per (bht, y). Gram q_row(32px) x k_rows(7x32px) via MFMA on RAW bf16,
// norms folded into the output scale. Outputs gathered into LDS tiles first,
// then written with coalesced 16B stores (the R0 2B-scatter was the bottleneck).
__global__ __launch_bounds__(256, 2) void k_corr(
    const short* __restrict__ qkvb, short* __restrict__ corrI, short* __restrict__ corrU)
{
  __shared__ short lq[32 * 64];    // q row, swizzled rows of 128B
  __shared__ short lk[224 * 64];   // k rows p = dy*32+xx
  __shared__ short tI[32 * 64];    // out tile [x][u]
  __shared__ short tU[64 * 32];    // out tile [u][x]
  __shared__ float sq[32];
  __shared__ float sk[224];

  const int tid = threadIdx.x;
  const int lane = tid & 63, w = tid >> 6;
  const int r15 = lane & 15, hi = (lane >> 4) * 16, g4 = (lane >> 4) * 4;
  const int y = blockIdx.x & 31, bht = blockIdx.x >> 5;
  const int b = bht >> 6, head = (bht >> 3) & 7, tf = bht & 7;
  const int tk = (tf < 7) ? tf + 1 : 7;

  // zero-init output tiles (2048 + 2048 shorts = 512 bf16x8)
  *(bf16x8*)(tI + tid * 8) = (bf16x8)(short)0;
  *(bf16x8*)(tU + (tid & 255) * 8) = (bf16x8)(short)0;  // tU is 2048 shorts = 256 chunks

  { // stage q: 32 rows x 128B = 256 chunks (1/thread)
    int row = tid >> 3;
    int sb = ((tid & 7) * 16) ^ ((row & 7) << 4);
    const char* src = (const char*)(qkvb + ((size_t)b * NTOK + tf * HW + y * 32 + row) * 1536 + head * 64) + sb;
    gl_lds16(src, lq + (w * 64) * 8);
  }
#pragma unroll
  for (int it = 0; it < 7; it++) { // stage k: 224 rows = 1792 chunks (7/thread)
    int chunk = it * 256 + tid;
    int row = chunk >> 3;          // p = dy*32+xx
    int dy = row >> 5, xx = row & 31;
    int ysrc = y + dy - 3;
    int sb = ((chunk & 7) * 16) ^ ((row & 7) << 4);
    short* dstbase = lk + (it * 256 + w * 64) * 8;
    if (ysrc >= 0 && ysrc < 32) {
      const char* src = (const char*)(qkvb + ((size_t)b * NTOK + tk * HW + ysrc * 32 + xx) * 1536 + 512 + head * 64) + sb;
      gl_lds16(src, dstbase);
    } else {
      *(bf16x8*)(lk + (size_t)chunk * 8) = (bf16x8)(short)0;  // zero pad (swizzle moot)
    }
  }
  asm volatile("s_waitcnt vmcnt(0)" ::: "memory");
  __syncthreads();

  // ones at u=49 (after zero-init barrier)
  if (tid < 32) tI[tid * 64 + 49] = f2bf(1.f);
  else if (tid < 64) tU[49 * 32 + (tid - 32)] = f2bf(1.f);

  { // norms: thread t<32 -> q pixel t; else k pixel t-32. scale = 1/(8*max(n,eps))
    int r = (tid < 32) ? tid : tid - 32;
    const short* base = (tid < 32) ? lq : lk;
    float ss = 0.f;
#pragma unroll
    for (int jj = 0; jj < 8; jj++) {
      int off = r * 128 + ((jj * 16) ^ ((r & 7) << 4));
      bf16x8 vv = *(const bf16x8*)((const char*)base + off);
#pragma unroll
      for (int e = 0; e < 8; e++) { float f = bf2f(vv[e]); ss += f * f; }
    }
    float nrm = fmaxf(sqrtf(ss), 1e-12f);
    float sc = 1.f / (8.f * nrm);
    if (tid < 32) sq[tid] = sc; else sk[tid - 32] = sc;
  }
  __syncthreads();

  // MFMA: 2 m-tiles x 14 n-tiles, wave w owns tiles t = w*7 .. w*7+6
  bf16x8 aq[2][2];
#pragma unroll
  for (int mt = 0; mt < 2; mt++) {
    int row = mt * 16 + r15;
#pragma unroll
    for (int kh = 0; kh < 2; kh++) {
      int off = row * 128 + ((kh * 64 + hi) ^ ((row & 7) << 4));
      aq[mt][kh] = *(const bf16x8*)((const char*)lq + off);
    }
  }
  f32x4 accc[7];
#pragma unroll
  for (int c = 0; c < 7; c++) {
    int t = w * 7 + c, mt = t & 1, nt = t >> 1;
    int rowB = nt * 16 + r15;
    f32x4 a = (f32x4)0.f;
#pragma unroll
    for (int kh = 0; kh < 2; kh++) {
      int off = rowB * 128 + ((kh * 64 + hi) ^ ((rowB & 7) << 4));
      bf16x8 bb = *(const bf16x8*)((const char*)lk + off);
      a = MFMA(aq[mt][kh], bb, a);
    }
    accc[c] = a;
  }

  // extract banded diagonals into LDS tiles: acc[x][p], p=dy*32+xx, keep |xx-x|<=3
#pragma unroll
  for (int c = 0; c < 7; c++) {
    int t = w * 7 + c, mt = t & 1, nt = t >> 1;
    int p = nt * 16 + r15;
    int dy = p >> 5, xx = p & 31;
    float skv = sk[p];
#pragma unroll
    for (int j = 0; j < 4; j++) {
      int xr = mt * 16 + g4 + j;
      int dx = xx - xr + 3;
      if (dx >= 0 && dx < 7) {
        int u = dy * 7 + dx;
        short bv = f2bf(accc[c][j] * sq[xr] * skv);
        tI[xr * 64 + u] = bv;
        tU[u * 32 + xr] = bv;
      }
    }
  }
  __syncthreads();

  // coalesced writeback: corrI rows i=y*32..y*32+31 are one contiguous 8KB block
  *(bf16x8*)(corrI + ((size_t)bht * HW + y * 32) * 64 + tid * 8) = *(const bf16x8*)(tI + tid * 8);
  { // corrU: 64 rows x 64B at stride 2KB, 4 lanes per row
    int u = tid >> 2, qq = tid & 3;
    *(bf16x8*)(corrU + (size_t)bht * 65536 + u * HW + y * 32 + qq * 8) = *(const bf16x8*)(tU + u * 32 + qq * 8);
  }
}

// ----------------------------------------------- v transpose: vT[bht][d][i]
__global__ __launch_bounds__(256, 2) void k_vT(const short* __restrict__ qkvb, short* __restrict__ vT)
{
  __shared__ short lt[128 * 72];  // [i][d] pad 72
  const int tid = threadIdx.x;
  const int bht = blockIdx.x >> 2;
  const int cbase = (blockIdx.x & 3) * 256;
  const int b = bht >> 6, head = (bht >> 3) & 7, tf = bht & 7;
  const size_t rowbase = ((size_t)b * NTOK + tf * HW) * 1536 + 1024 + head * 64;
  for (int c0 = cbase; c0 < cbase + 256; c0 += 128) {
    __syncthreads();
#pragma unroll
    for (int it = 0; it < 4; it++) {
      int idx = it * 256 + tid;
      int row = idx >> 3, part = idx & 7;
      bf16x8 v = *(const bf16x8*)(qkvb + rowbase + (size_t)(c0 + row) * 1536 + part * 8);
      *(bf16x8*)(lt + row * 72 + part * 8) = v;
    }
    __syncthreads();
    int d = tid & 63, blk = tid >> 6;
#pragma unroll
    for (int qq = 0; qq < 4; qq++) {
      bf16x8 o;
#pragma unroll
      for (int e = 0; e < 8; e++) o[e] = lt[(blk * 32 + qq * 8 + e) * 72 + d];
      *(bf16x8*)(vT + ((size_t)bht * 64 + d) * HW + c0 + blk * 32 + qq * 8) = o;
    }
  }
}

// --------------------------------- fused rank-50 attention, one WG per bht
// phase1: GT[d][u] = sum_i vT[d][i]*corrU[u][i]   (K=1024, MFMA)
//         c1[u]    = sum_i corrU[u][i]            (VALU, tiles already in LDS)
// phase2: out[i][d] = (corrI[i][:] . GT[d][:]) / (corrI[i][:] . c1[:])
__global__ __launch_bounds__(256, 2) void k_attn(
    const short* __restrict__ corrU, const short* __restrict__ corrI,
    const short* __restrict__ vT, short* __restrict__ out_attn)
{
  __shared__ short lV[64 * 64];
  __shared__ short lU[64 * 64];
  __shared__ short GTl[64 * 72];
  __shared__ float cl[64];
  __shared__ float cpart[256];
  const int tid = threadIdx.x, lane = tid & 63, w = tid >> 6;
  const int r15 = lane & 15, hi = (lane >> 4) * 16, g4 = (lane >> 4) * 4, g8 = (lane >> 4) * 8;
  const int bht = blockIdx.x;
  const int b = bht >> 6, head = (bht >> 3) & 7, tf = bht & 7;

  f32x4 accP[4];
#pragma unroll
  for (int nt = 0; nt < 4; nt++) accP[nt] = (f32x4)0.f;
  float c1p = 0.f;
  const short* vbase = vT + (size_t)bht * 64 * HW;
  const short* ubase = corrU + (size_t)bht * 65536;

  for (int i0 = 0; i0 < 1024; i0 += 64) {
#pragma unroll
    for (int it = 0; it < 2; it++) {
      int chunk = it * 256 + tid;
      int row = chunk >> 3;
      int sb = ((chunk & 7) * 16) ^ ((row & 7) << 4);
      gl_lds16((const char*)(vbase + (size_t)row * HW + i0) + sb, lV + (it * 256 + w * 64) * 8);
      gl_lds16((const char*)(ubase + (size_t)row * HW + i0) + sb, lU + (it * 256 + w * 64) * 8);
    }
    asm volatile("s_waitcnt vmcnt(0)" ::: "memory");
    __syncthreads();
    bf16x8 av[2];
    int rowA = w * 16 + r15;
#pragma unroll
    for (int kh = 0; kh < 2; kh++) {
      int off = rowA * 128 + ((kh * 64 + hi) ^ ((rowA & 7) << 4));
      av[kh] = *(const bf16x8*)((const char*)lV + off);
    }
#pragma unroll
    for (int nt = 0; nt < 4; nt++) {
      int rowB = nt * 16 + r15;
#pragma unroll
      for (int kh = 0; kh < 2; kh++) {
        int off = rowB * 128 + ((kh * 64 + hi) ^ ((rowB & 7) << 4));
        bf16x8 bu = *(const bf16x8*)((const char*)lU + off);
        accP[nt] = MFMA(av[kh], bu, accP[nt]);
      }
    }
    { // c1 partials: thread t sums lU row u=t>>2, 16 elems at part=(t&3)
      int u = tid >> 2, part = tid & 3;
#pragma unroll
      for (int h = 0; h < 2; h++) {
        int off = u * 128 + ((part * 32 + h * 16) ^ ((u & 7) << 4));
        bf16x8 vv = *(const bf16x8*)((const char*)lU + off);
#pragma unroll
        for (int e = 0; e < 8; e++) c1p += bf2f(vv[e]);
      }
    }
    __syncthreads();
  }
  cpart[tid] = c1p;
#pragma unroll
  for (int nt = 0; nt < 4; nt++)
#pragma unroll
    for (int j = 0; j < 4; j++) {
      int d = w * 16 + g4 + j, u = nt * 16 + r15;
      GTl[d * 72 + u] = f2bf(accP[nt][j]);
    }
  __syncthreads();
  if (tid < 64) cl[tid] = cpart[4 * tid] + cpart[4 * tid + 1] + cpart[4 * tid + 2] + cpart[4 * tid + 3];
  __syncthreads();

  bf16x8 gtb[4][2];
#pragma unroll
  for (int nt = 0; nt < 4; nt++)
#pragma unroll
    for (int kh = 0; kh < 2; kh++)
      gtb[nt][kh] = *(const bf16x8*)((const char*)GTl + (nt * 16 + r15) * 144 + kh * 64 + hi);

  float c1r[2][8];
#pragma unroll
  for (int kh = 0; kh < 2; kh++)
#pragma unroll
    for (int e = 0; e < 8; e++) c1r[kh][e] = cl[kh * 32 + g8 + e];

  const short* ibase = corrI + (size_t)bht * HW * 64;
  for (int s = 0; s < 16; s++) {
    int i0 = w * 256 + s * 16;
    bf16x8 af[2];
#pragma unroll
    for (int kh = 0; kh < 2; kh++)
      af[kh] = *(const bf16x8*)(ibase + (size_t)(i0 + r15) * 64 + kh * 32 + g8);
    f32x4 a2[4];
#pragma unroll
    for (int nt = 0; nt < 4; nt++) a2[nt] = (f32x4)0.f;
#pragma unroll
    for (int nt = 0; nt < 4; nt++)
#pragma unroll
      for (int kh = 0; kh < 2; kh++) a2[nt] = MFMA(af[kh], gtb[nt][kh], a2[nt]);

    float dp = 0.f;
#pragma unroll
    for (int kh = 0; kh < 2; kh++)
#pragma unroll
      for (int e = 0; e < 8; e++) dp += bf2f(af[kh][e]) * c1r[kh][e];
    dp += __shfl_xor(dp, 16);
    dp += __shfl_xor(dp, 32);   // lanes sharing (lane&15) now hold full denom of row i0+(lane&15)

#pragma unroll
    for (int j = 0; j < 4; j++) {
      float dj = __shfl(dp, g4 + j);
      float inv = 1.f / dj;
      int i = i0 + g4 + j;
      size_t outrow = ((size_t)b * NTOK + tf * HW + i) * 512 + head * 64;
#pragma unroll
      for (int nt = 0; nt < 4; nt++)
        out_attn[outrow + nt * 16 + r15] = f2bf(a2[nt][j] * inv);
    }
  }
}

extern "C" void kernel_launch(void* const* d_in, const int* in_sizes, int n_in,
                              void* d_out, int out_size, void* d_ws, size_t ws_size,
                              hipStream_t stream) {
  (void)in_sizes; (void)n_in; (void)out_size; (void)ws_size;
  const float* x      = (const float*)d_in[0];
  const float* w_qkv  = (const float*)d_in[1];
  const float* w_proj = (const float*)d_in[2];
  const float* b_proj = (const float*)d_in[3];

  char* ws = (char*)d_ws;                       // total needed: ~98.0 MB
  short* qkvb   = (short*)(ws);                 // 50,331,648 B [16384][1536]
  short* xb     = (short*)(ws + 50331648);      // 16,777,216 B
  short* corrU  = (short*)(ws + 67108864);      // 16,777,216 B [128][64][1024]
  short* vT     = (short*)(ws + 83886080);      // 16,777,216 B [128][64][1024]
  short* wqkvb  = (short*)(ws + 100663296);     //  1,572,864 B
  short* wprojb = (short*)(ws + 102236160);     //    524,288 B
  short* corrI    = xb;    // alias: xb dead after qkv GEMM
  short* out_attn = qkvb;  // alias: qkvb dead after corr + vT

  k_cvt<<<dim3(4096), 256, 0, stream>>>(x, xb, 1048576);
  k_cvt<<<dim3(384),  256, 0, stream>>>(w_qkv, wqkvb, 98304);
  k_cvt<<<dim3(128),  256, 0, stream>>>(w_proj, wprojb, 32768);

  k_gemm_bt<0><<<dim3(12, 128), 256, 0, stream>>>(xb, wqkvb, qkvb, nullptr, 16384, 1536, 512);

  k_corr<<<dim3(4096), 256, 0, stream>>>(qkvb, corrI, corrU);
  k_vT<<<dim3(512), 256, 0, stream>>>(qkvb, vT);

  k_attn<<<dim3(128), 256, 0, stream>>>(corrU, corrI, vT, out_attn);

  k_gemm_bt<1><<<dim3(4, 128), 256, 0, stream>>>(out_attn, wprojb, d_out, b_proj, 16384, 512, 512);
}